// Round 13
// baseline (255.606 us; speedup 1.0000x reference)
//
#include <hip/hip_runtime.h>
#include <hip/hip_bf16.h>
#include <math.h>

// B=2, L=2048, D=1024, H=16, Dh=64. M = B*L = 4096.
// prep_all: x -> bf16 SWIZZLED xsw; w_qkv/w_proj -> bf16 transposed SWIZZLED; rope table; mask bits
// gemm<0>:  xsw @ wqT + RoPE -> q*(0.125*log2e) (natural), k (row-XOR), v^T (PLAIN [d][kv])
// attn:     flash attention: K via 2-deep LDS, V direct from L2, 4 waves x 16 q-rows, grid 1024
// gemm<1>:  ob @ wpT -> f32 d_out

typedef __attribute__((ext_vector_type(8))) short bf16x8;
typedef __attribute__((ext_vector_type(4))) float f32x4;

__device__ __forceinline__ unsigned short f2bf(float f) {
    union { float f; unsigned int u; } v; v.f = f;
    unsigned int u = v.u;
    return (unsigned short)((u + 0x7FFFu + ((u >> 16) & 1u)) >> 16);
}

__device__ __forceinline__ unsigned short bfc(float f) {
    union { __hip_bfloat16 h; unsigned short u; } c;
    c.h = __float2bfloat16(f);
    return c.u;
}

__device__ __forceinline__ void gload_lds16(const unsigned short* g, unsigned short* l) {
    __builtin_amdgcn_global_load_lds(
        (const __attribute__((address_space(1))) void*)g,
        (__attribute__((address_space(3))) void*)l, 16, 0, 0);
}

// ---- fused prep: [0,2048) xbf | [2048,5120) wqT | [5120,6144) wpT | [6144,6400) rope | 6400 mbits ----
__global__ __launch_bounds__(256) void prep_all(
    const float* __restrict__ x, const float* __restrict__ w_qkv, const float* __restrict__ w_proj,
    const int* __restrict__ mask,
    unsigned short* __restrict__ xsw, unsigned short* __restrict__ wqT,
    unsigned short* __restrict__ wpT, float2* __restrict__ tab,
    unsigned long long* __restrict__ mb)
{
    __shared__ unsigned short t[32][34];
    int bid = blockIdx.x, tid = threadIdx.x;
    if (bid < 2048) {
        int i = bid * 256 + tid;
        int row = i >> 7, blk = i & 127;
        int swblk = (blk & ~7) | ((blk ^ row) & 7);
        const float* src = x + ((size_t)row << 10) + (blk << 3);
        float4 f0 = *(const float4*)(src);
        float4 f1 = *(const float4*)(src + 4);
        ushort4 h0, h1;
        h0.x = f2bf(f0.x); h0.y = f2bf(f0.y); h0.z = f2bf(f0.z); h0.w = f2bf(f0.w);
        h1.x = f2bf(f1.x); h1.y = f2bf(f1.y); h1.z = f2bf(f1.z); h1.w = f2bf(f1.w);
        ushort4* dst = (ushort4*)(xsw + ((size_t)row << 10) + (swblk << 3));
        dst[0] = h0; dst[1] = h1;
    } else if (bid < 6144) {
        const float* w; unsigned short* wT; int Ncols, u;
        if (bid < 5120) { w = w_qkv; wT = wqT; Ncols = 3072; u = bid - 2048; }
        else            { w = w_proj; wT = wpT; Ncols = 1024; u = bid - 5120; }
        int NBx = Ncols >> 5;
        int n0 = (u % NBx) * 32, k0 = (u / NBx) * 32;
        int r = tid >> 3, c4 = (tid & 7) * 4;
        float4 f = *(const float4*)(w + (size_t)(k0 + r) * Ncols + n0 + c4);
        t[c4 + 0][r] = f2bf(f.x);
        t[c4 + 1][r] = f2bf(f.y);
        t[c4 + 2][r] = f2bf(f.z);
        t[c4 + 3][r] = f2bf(f.w);
        __syncthreads();
        ushort4 o;
        o.x = t[r][c4]; o.y = t[r][c4 + 1]; o.z = t[r][c4 + 2]; o.w = t[r][c4 + 3];
        int n = n0 + r, k = k0 + c4;
        int ksw = (k & ~63) | ((((k >> 3) ^ n) & 7) << 3) | (k & 7);
        *(ushort4*)(wT + (size_t)n * 1024 + ksw) = o;
    } else if (bid < 6400) {
        int i = (bid - 6144) * 256 + tid;
        int pos = i >> 5, d = i & 31;
        float inv = expf(-0.28782313662f * (float)d);
        float ang = (float)pos * inv;
        float s, c;
        sincosf(ang, &s, &c);
        tab[i] = make_float2(c, s);
    } else if (tid < 64) {
        int b = tid >> 5, w = tid & 31;
        unsigned long long bits = 0;
        #pragma unroll 8
        for (int j = 0; j < 64; ++j)
            if (mask[b * 2048 + w * 64 + j]) bits |= (1ULL << j);
        mb[tid] = bits;
    }
}

// ---- main GEMM: 128x128 tile, BK=64, both operands bf16 swizzled via global_load_lds ----
template<int MODE>
__global__ __launch_bounds__(256) void gemm_kernel(
    const unsigned short* __restrict__ Asw, const unsigned short* __restrict__ BT,
    const float2* __restrict__ ropetab,
    unsigned short* __restrict__ qb, unsigned short* __restrict__ kb,
    unsigned short* __restrict__ vb, float* __restrict__ Cout, int N)
{
    const int K = 1024;
    __shared__ __align__(16) unsigned short As[128 * 64];
    __shared__ __align__(16) unsigned short Bs[128 * 64];
    int tid = threadIdx.x;
    int wid = tid >> 6, lane = tid & 63, lr = lane & 15, lg = lane >> 4;
    int wm = (wid >> 1) * 64, wn = (wid & 1) * 64;

    int NB = N >> 7;
    int per = NB * 4;
    int flat = blockIdx.x;
    int w = (flat & 7) * per + (flat >> 3);
    int row0 = (w / NB) * 128, col0 = (w % NB) * 128;

    int swk = (lr & 7) << 3;

    f32x4 acc[4][4];
    #pragma unroll
    for (int m = 0; m < 4; ++m)
        #pragma unroll
        for (int n = 0; n < 4; ++n)
            #pragma unroll
            for (int i = 0; i < 4; ++i) acc[m][n][i] = 0.0f;

    for (int k0 = 0; k0 < K; k0 += 64) {
        #pragma unroll
        for (int i = 0; i < 4; ++i) {
            int cbase = (i * 4 + wid) * 64;
            int c = cbase + lane;
            int r = c >> 3, cc = (c & 7) * 8;
            gload_lds16(BT + (size_t)(col0 + r) * K + k0 + cc, Bs + cbase * 8);
            gload_lds16(Asw + (size_t)(row0 + r) * K + k0 + cc, As + cbase * 8);
        }
        __syncthreads();
        #pragma unroll
        for (int kk = 0; kk < 2; ++kk) {
            bf16x8 af[4], bfr[4];
            #pragma unroll
            for (int m = 0; m < 4; ++m)
                af[m] = *(const bf16x8*)(&As[(wm + m * 16 + lr) * 64 + ((kk * 32 + lg * 8) ^ swk)]);
            #pragma unroll
            for (int n = 0; n < 4; ++n)
                bfr[n] = *(const bf16x8*)(&Bs[(wn + n * 16 + lr) * 64 + ((kk * 32 + lg * 8) ^ swk)]);
            #pragma unroll
            for (int m = 0; m < 4; ++m)
                #pragma unroll
                for (int n = 0; n < 4; ++n)
                    acc[m][n] = __builtin_amdgcn_mfma_f32_16x16x32_bf16(af[m], bfr[n], acc[m][n], 0, 0, 0);
        }
        __syncthreads();
    }

    if (MODE == 1) {
        #pragma unroll
        for (int m = 0; m < 4; ++m)
            #pragma unroll
            for (int reg = 0; reg < 4; ++reg) {
                int grow = row0 + wm + m * 16 + lg * 4 + reg;
                #pragma unroll
                for (int n = 0; n < 4; ++n)
                    Cout[(size_t)grow * N + col0 + wn + n * 16 + lr] = acc[m][n][reg];
            }
    } else {
        #pragma unroll
        for (int m = 0; m < 4; ++m)
            #pragma unroll
            for (int reg = 0; reg < 4; ++reg) {
                int grow = row0 + wm + m * 16 + lg * 4 + reg;
                int pos = grow & 2047;
                int bb = grow >> 11;
                #pragma unroll
                for (int n = 0; n < 4; ++n) {
                    int col = col0 + wn + n * 16 + lr;
                    int part = col >> 10;           // 0=q 1=k 2=v
                    int h = (col >> 6) & 15;
                    int d = col & 63;
                    float v0 = acc[m][n][reg];
                    if (part == 2) {
                        // v^T PLAIN [d][kv] (V read from L2 by attn, no swizzle needed)
                        vb[((size_t)bb * 16 + h) * 131072 + (size_t)d * 2048 + pos] = f2bf(v0);
                    } else if (n < 2) {             // d<32, partner at n+2 (d+32) same lane
                        float v1 = acc[m][n + 2][reg];
                        float2 cs = ropetab[pos * 32 + d];
                        size_t base = (((size_t)bb * 16 + h) * 2048 + pos) * 64;
                        float e0 = v0 * cs.x - v1 * cs.y;
                        float e1 = v1 * cs.x + v0 * cs.y;
                        if (part == 0) {            // q: fold softmax scale AND log2(e) for exp2 softmax
                            qb[base + d]      = f2bf(e0 * 0.18033688f);
                            qb[base + d + 32] = f2bf(e1 * 0.18033688f);
                        } else {                    // k row-swizzled
                            int sw = (pos & 7) << 3;
                            kb[base + (d ^ sw)]        = f2bf(e0);
                            kb[base + ((d + 32) ^ sw)] = f2bf(e1);
                        }
                    }
                }
            }
    }
}

// ---- flash attention v9: K via 2-deep LDS; V direct from L2; 4 waves x 16 q-rows ----
#define PST 68   // Ps row stride (ushorts)
__global__ __launch_bounds__(256, 5) void attn_kernel(
    const unsigned short* __restrict__ qbuf, const unsigned short* __restrict__ kbuf,
    const unsigned short* __restrict__ vtbuf, const unsigned long long* __restrict__ mbits,
    unsigned short* __restrict__ obuf)
{
    __shared__ __align__(16) unsigned short Ks[2][4096];   // [kvl][d^swz] 64x64
    __shared__ __align__(16) unsigned short Ps[4][16][PST];

    // XCD-chunked remap: 1024 blocks, 8 XCDs, 128 consecutive w per XCD (4 bh -> 2MB K/V in L2)
    int flat = blockIdx.x;
    int w = ((flat & 7) << 7) + (flat >> 3);
    int bh = w >> 5, qt = w & 31;
    int b = bh >> 4, h = bh & 15;
    int tid = threadIdx.x, wid = tid >> 6, lane = tid & 63, lr = lane & 15, lg = lane >> 4;
    int qrow0 = qt * 64 + wid * 16;
    const size_t bhbase = (size_t)bh * (2048 * 64);
    const unsigned short* kB = kbuf + bhbase;
    const unsigned short* vt = vtbuf + bhbase;   // [64][2048] plain
    const unsigned long long* mw = mbits + (b << 5);
    unsigned short* prow = &Ps[wid][lr][0];
    int sw3 = lr & 3;
    int swk = (lr & 7) << 3;

    bf16x8 qf[2];
    #pragma unroll
    for (int kk = 0; kk < 2; ++kk)
        qf[kk] = *(const bf16x8*)(qbuf + bhbase + (size_t)(qrow0 + lr) * 64 + kk * 32 + lg * 8);

    f32x4 oacc[4];
    #pragma unroll
    for (int n = 0; n < 4; ++n)
        #pragma unroll
        for (int i = 0; i < 4; ++i) oacc[n][i] = 0.0f;
    float mrow = -INFINITY, lrow = 0.f;   // lrow stays LANE-PARTIAL until epilogue
    const f32x4 z4 = {0.f, 0.f, 0.f, 0.f};

    auto stage = [&](int t, unsigned short* Kb) {
        #pragma unroll
        for (int i = 0; i < 2; ++i)
            gload_lds16(kB + (size_t)t * 4096 + (i * 256 + tid) * 8, Kb + (i * 256 + wid * 64) * 8);
    };

    unsigned short *Kcur = Ks[0], *Knxt = Ks[1];

    stage(0, Kcur);
    #pragma unroll 1
    for (int t = 0; t < 32; ++t) {
        __syncthreads();                  // staging of (t) complete; prior reads done
        if (t < 31) stage(t + 1, Knxt);
        unsigned long long bb = mw[t];    // wave-uniform mask word

        // V fragments direct from L2 (issued early; consumed after softmax ~600cy later)
        bf16x8 vf[2][4];
        #pragma unroll
        for (int kk2 = 0; kk2 < 2; ++kk2)
            #pragma unroll
            for (int n = 0; n < 4; ++n)
                vf[kk2][n] = *(const bf16x8*)(vt + (size_t)(n * 16 + lr) * 2048 + t * 64 + kk2 * 32 + lg * 8);

        // K fragments (A-operand) + QK^T
        __builtin_amdgcn_s_setprio(1);
        f32x4 sacc[4];
        #pragma unroll
        for (int kk = 0; kk < 2; ++kk)
            #pragma unroll
            for (int n = 0; n < 4; ++n) {
                bf16x8 kfx = *(const bf16x8*)(Kcur + (n * 16 + lr) * 64 + ((kk * 32 + lg * 8) ^ swk));
                sacc[n] = (kk == 0)
                    ? __builtin_amdgcn_mfma_f32_16x16x32_bf16(kfx, qf[0], z4, 0, 0, 0)
                    : __builtin_amdgcn_mfma_f32_16x16x32_bf16(kfx, qf[1], sacc[n], 0, 0, 0);
            }
        __builtin_amdgcn_s_setprio(0);

        // mask (fast path when all 64 live)
        if (bb != ~0ULL) {
            #pragma unroll
            for (int n = 0; n < 4; ++n)
                #pragma unroll
                for (int reg = 0; reg < 4; ++reg) {
                    int kv = n * 16 + lg * 4 + reg;
                    if (!((bb >> kv) & 1)) sacc[n][reg] = -1e30f;
                }
        }

        // lane-local max; cross-lane reduce+rescale only when defer bound threatened
        float a0 = fmaxf(fmaxf(sacc[0][0], sacc[0][1]), fmaxf(sacc[0][2], sacc[0][3]));
        float a1 = fmaxf(fmaxf(sacc[1][0], sacc[1][1]), fmaxf(sacc[1][2], sacc[1][3]));
        float a2 = fmaxf(fmaxf(sacc[2][0], sacc[2][1]), fmaxf(sacc[2][2], sacc[2][3]));
        float a3 = fmaxf(fmaxf(sacc[3][0], sacc[3][1]), fmaxf(sacc[3][2], sacc[3][3]));
        float tmax = fmaxf(fmaxf(a0, a1), fmaxf(a2, a3));
        if (__any(tmax > mrow + 8.f)) {    // slow path (rare after tile 0)
            float tr = fmaxf(tmax, __shfl_xor(tmax, 16));
            tr = fmaxf(tr, __shfl_xor(tr, 32));
            float mnew = fmaxf(mrow, tr);
            float sc = (mrow == -INFINITY) ? 0.f : __builtin_amdgcn_exp2f(mrow - mnew);
            lrow *= sc;
            mrow = mnew;
            #pragma unroll
            for (int reg = 0; reg < 4; ++reg) {
                float scq = __shfl(sc, lg * 4 + reg);
                #pragma unroll
                for (int n = 0; n < 4; ++n) oacc[n][reg] *= scq;
            }
        }

        // P = exp2(S - m), lane-partial sum, pack, swizzled Ps store
        float ps = 0.f;
        #pragma unroll
        for (int n = 0; n < 4; ++n) {
            float p0 = __builtin_amdgcn_exp2f(sacc[n][0] - mrow);
            float p1 = __builtin_amdgcn_exp2f(sacc[n][1] - mrow);
            float p2 = __builtin_amdgcn_exp2f(sacc[n][2] - mrow);
            float p3 = __builtin_amdgcn_exp2f(sacc[n][3] - mrow);
            ps += (p0 + p1) + (p2 + p3);
            ushort4 wv;
            wv.x = bfc(p0); wv.y = bfc(p1); wv.z = bfc(p2); wv.w = bfc(p3);
            int gb = 2 * n + (lg >> 1);
            int col = ((gb ^ sw3) << 3) + (lg & 1) * 4;
            *(ushort4*)(prow + col) = wv;
        }
        lrow += ps;                        // no shuffle: deferred to epilogue

        // P fragments (A-operand) and PV with L2-fetched V
        bf16x8 pf[2];
        #pragma unroll
        for (int kk2 = 0; kk2 < 2; ++kk2)
            pf[kk2] = *(const bf16x8*)(prow + (((kk2 * 4 + lg) ^ sw3) << 3));
        __builtin_amdgcn_s_setprio(1);
        #pragma unroll
        for (int kk2 = 0; kk2 < 2; ++kk2)
            #pragma unroll
            for (int n = 0; n < 4; ++n)
                oacc[n] = __builtin_amdgcn_mfma_f32_16x16x32_bf16(pf[kk2], vf[kk2][n], oacc[n], 0, 0, 0);
        __builtin_amdgcn_s_setprio(0);

        // swap 2-deep K buffer
        unsigned short* tK = Kcur; Kcur = Knxt; Knxt = tK;
    }

    // complete the deferred l reduction
    lrow += __shfl_xor(lrow, 16);
    lrow += __shfl_xor(lrow, 32);

    // epilogue: O rows q = lg*4+reg, cols d = n*16+lr; ob written PRE-SWIZZLED for gemm1
    #pragma unroll
    for (int reg = 0; reg < 4; ++reg) {
        float lq = __shfl(lrow, lg * 4 + reg);
        float linv = 1.0f / lq;
        int qrow = qrow0 + lg * 4 + reg;
        int qsw = qrow & 7;
        #pragma unroll
        for (int n = 0; n < 4; ++n) {
            int jj = n * 2 + (lr >> 3);
            int colsw = h * 64 + (((jj ^ qsw) & 7) << 3) + (lr & 7);
            obuf[((size_t)b * 2048 + qrow) * 1024 + colsw] = bfc(oacc[n][reg] * linv);
        }
    }
}

extern "C" void kernel_launch(void* const* d_in, const int* in_sizes, int n_in,
                              void* d_out, int out_size, void* d_ws, size_t ws_size,
                              hipStream_t stream) {
    const float* x      = (const float*)d_in[0];
    const int* key_mask = (const int*)d_in[1];
    const float* w_qkv  = (const float*)d_in[2];
    const float* w_proj = (const float*)d_in[3];
    float* out = (float*)d_out;

    char* ws = (char*)d_ws;
    unsigned short* qb  = (unsigned short*)(ws);
    unsigned short* kb  = (unsigned short*)(ws + 8388608);
    unsigned short* vtb = (unsigned short*)(ws + 16777216);
    unsigned short* xob = (unsigned short*)(ws + 25165824);  // xsw for gemm0, then ob for gemm1
    unsigned short* wqT = (unsigned short*)(ws + 33554432);
    unsigned short* wpT = (unsigned short*)(ws + 39845888);
    float2*         tab = (float2*)(ws + 41943040);
    unsigned long long* mb = (unsigned long long*)(ws + 42467328);

    dim3 blk(256);
    prep_all<<<dim3(6401), blk, 0, stream>>>(x, w_qkv, w_proj, key_mask, xob, wqT, wpT, tab, mb);
    gemm_kernel<0><<<dim3(768), blk, 0, stream>>>(xob, wqT, tab, qb, kb, vtb, nullptr, 3072);
    attn_kernel<<<dim3(1024), blk, 0, stream>>>(qb, kb, vtb, mb, xob);
    gemm_kernel<1><<<dim3(256), blk, 0, stream>>>(xob, wpT, nullptr, nullptr, nullptr, nullptr, out, 1024);
}

// Round 14
// 155.770 us; speedup vs baseline: 1.6409x; 1.6409x over previous
//
#include <hip/hip_runtime.h>
#include <hip/hip_bf16.h>
#include <math.h>

// B=2, L=2048, D=1024, H=16, Dh=64. M = B*L = 4096.
// prep_all: x -> bf16 SWIZZLED xsw; w_qkv/w_proj -> bf16 transposed SWIZZLED; rope table; mask bits
// gemm<0>:  xsw @ wqT + RoPE -> q*(0.125*log2e) (natural), k (row-XOR), v^T (row-tile-XOR)
// attn:     flash attention (swapped QK^T, 3-deep LDS K/V, deferred-PV, 8 waves x 16 q-rows)
// gemm<1>:  ob @ wpT -> f32 d_out

typedef __attribute__((ext_vector_type(8))) short bf16x8;
typedef __attribute__((ext_vector_type(4))) float f32x4;

__device__ __forceinline__ unsigned short f2bf(float f) {
    union { float f; unsigned int u; } v; v.f = f;
    unsigned int u = v.u;
    return (unsigned short)((u + 0x7FFFu + ((u >> 16) & 1u)) >> 16);
}

__device__ __forceinline__ unsigned short bfc(float f) {
    union { __hip_bfloat16 h; unsigned short u; } c;
    c.h = __float2bfloat16(f);
    return c.u;
}

__device__ __forceinline__ void gload_lds16(const unsigned short* g, unsigned short* l) {
    __builtin_amdgcn_global_load_lds(
        (const __attribute__((address_space(1))) void*)g,
        (__attribute__((address_space(3))) void*)l, 16, 0, 0);
}

// ---- fused prep: [0,2048) xbf | [2048,5120) wqT | [5120,6144) wpT | [6144,6400) rope | 6400 mbits ----
__global__ __launch_bounds__(256) void prep_all(
    const float* __restrict__ x, const float* __restrict__ w_qkv, const float* __restrict__ w_proj,
    const int* __restrict__ mask,
    unsigned short* __restrict__ xsw, unsigned short* __restrict__ wqT,
    unsigned short* __restrict__ wpT, float2* __restrict__ tab,
    unsigned long long* __restrict__ mb)
{
    __shared__ unsigned short t[32][34];
    int bid = blockIdx.x, tid = threadIdx.x;
    if (bid < 2048) {
        int i = bid * 256 + tid;
        int row = i >> 7, blk = i & 127;
        int swblk = (blk & ~7) | ((blk ^ row) & 7);
        const float* src = x + ((size_t)row << 10) + (blk << 3);
        float4 f0 = *(const float4*)(src);
        float4 f1 = *(const float4*)(src + 4);
        ushort4 h0, h1;
        h0.x = f2bf(f0.x); h0.y = f2bf(f0.y); h0.z = f2bf(f0.z); h0.w = f2bf(f0.w);
        h1.x = f2bf(f1.x); h1.y = f2bf(f1.y); h1.z = f2bf(f1.z); h1.w = f2bf(f1.w);
        ushort4* dst = (ushort4*)(xsw + ((size_t)row << 10) + (swblk << 3));
        dst[0] = h0; dst[1] = h1;
    } else if (bid < 6144) {
        const float* w; unsigned short* wT; int Ncols, u;
        if (bid < 5120) { w = w_qkv; wT = wqT; Ncols = 3072; u = bid - 2048; }
        else            { w = w_proj; wT = wpT; Ncols = 1024; u = bid - 5120; }
        int NBx = Ncols >> 5;
        int n0 = (u % NBx) * 32, k0 = (u / NBx) * 32;
        int r = tid >> 3, c4 = (tid & 7) * 4;
        float4 f = *(const float4*)(w + (size_t)(k0 + r) * Ncols + n0 + c4);
        t[c4 + 0][r] = f2bf(f.x);
        t[c4 + 1][r] = f2bf(f.y);
        t[c4 + 2][r] = f2bf(f.z);
        t[c4 + 3][r] = f2bf(f.w);
        __syncthreads();
        ushort4 o;
        o.x = t[r][c4]; o.y = t[r][c4 + 1]; o.z = t[r][c4 + 2]; o.w = t[r][c4 + 3];
        int n = n0 + r, k = k0 + c4;
        int ksw = (k & ~63) | ((((k >> 3) ^ n) & 7) << 3) | (k & 7);
        *(ushort4*)(wT + (size_t)n * 1024 + ksw) = o;
    } else if (bid < 6400) {
        int i = (bid - 6144) * 256 + tid;
        int pos = i >> 5, d = i & 31;
        float inv = expf(-0.28782313662f * (float)d);
        float ang = (float)pos * inv;
        float s, c;
        sincosf(ang, &s, &c);
        tab[i] = make_float2(c, s);
    } else if (tid < 64) {
        int b = tid >> 5, w = tid & 31;
        unsigned long long bits = 0;
        #pragma unroll 8
        for (int j = 0; j < 64; ++j)
            if (mask[b * 2048 + w * 64 + j]) bits |= (1ULL << j);
        mb[tid] = bits;
    }
}

// ---- main GEMM: 128x128 tile, BK=64, both operands bf16 swizzled via global_load_lds ----
template<int MODE>
__global__ __launch_bounds__(256) void gemm_kernel(
    const unsigned short* __restrict__ Asw, const unsigned short* __restrict__ BT,
    const float2* __restrict__ ropetab,
    unsigned short* __restrict__ qb, unsigned short* __restrict__ kb,
    unsigned short* __restrict__ vb, float* __restrict__ Cout, int N)
{
    const int K = 1024;
    __shared__ __align__(16) unsigned short As[128 * 64];
    __shared__ __align__(16) unsigned short Bs[128 * 64];
    int tid = threadIdx.x;
    int wid = tid >> 6, lane = tid & 63, lr = lane & 15, lg = lane >> 4;
    int wm = (wid >> 1) * 64, wn = (wid & 1) * 64;

    int NB = N >> 7;
    int per = NB * 4;
    int flat = blockIdx.x;
    int w = (flat & 7) * per + (flat >> 3);
    int row0 = (w / NB) * 128, col0 = (w % NB) * 128;

    int swk = (lr & 7) << 3;

    f32x4 acc[4][4];
    #pragma unroll
    for (int m = 0; m < 4; ++m)
        #pragma unroll
        for (int n = 0; n < 4; ++n)
            #pragma unroll
            for (int i = 0; i < 4; ++i) acc[m][n][i] = 0.0f;

    for (int k0 = 0; k0 < K; k0 += 64) {
        #pragma unroll
        for (int i = 0; i < 4; ++i) {
            int cbase = (i * 4 + wid) * 64;
            int c = cbase + lane;
            int r = c >> 3, cc = (c & 7) * 8;
            gload_lds16(BT + (size_t)(col0 + r) * K + k0 + cc, Bs + cbase * 8);
            gload_lds16(Asw + (size_t)(row0 + r) * K + k0 + cc, As + cbase * 8);
        }
        __syncthreads();
        #pragma unroll
        for (int kk = 0; kk < 2; ++kk) {
            bf16x8 af[4], bfr[4];
            #pragma unroll
            for (int m = 0; m < 4; ++m)
                af[m] = *(const bf16x8*)(&As[(wm + m * 16 + lr) * 64 + ((kk * 32 + lg * 8) ^ swk)]);
            #pragma unroll
            for (int n = 0; n < 4; ++n)
                bfr[n] = *(const bf16x8*)(&Bs[(wn + n * 16 + lr) * 64 + ((kk * 32 + lg * 8) ^ swk)]);
            #pragma unroll
            for (int m = 0; m < 4; ++m)
                #pragma unroll
                for (int n = 0; n < 4; ++n)
                    acc[m][n] = __builtin_amdgcn_mfma_f32_16x16x32_bf16(af[m], bfr[n], acc[m][n], 0, 0, 0);
        }
        __syncthreads();
    }

    if (MODE == 1) {
        #pragma unroll
        for (int m = 0; m < 4; ++m)
            #pragma unroll
            for (int reg = 0; reg < 4; ++reg) {
                int grow = row0 + wm + m * 16 + lg * 4 + reg;
                #pragma unroll
                for (int n = 0; n < 4; ++n)
                    Cout[(size_t)grow * N + col0 + wn + n * 16 + lr] = acc[m][n][reg];
            }
    } else {
        #pragma unroll
        for (int m = 0; m < 4; ++m)
            #pragma unroll
            for (int reg = 0; reg < 4; ++reg) {
                int grow = row0 + wm + m * 16 + lg * 4 + reg;
                int pos = grow & 2047;
                int bb = grow >> 11;
                #pragma unroll
                for (int n = 0; n < 4; ++n) {
                    int col = col0 + wn + n * 16 + lr;
                    int part = col >> 10;           // 0=q 1=k 2=v
                    int h = (col >> 6) & 15;
                    int d = col & 63;
                    float v0 = acc[m][n][reg];
                    if (part == 2) {
                        int posl = (pos & 63) ^ ((d & 7) << 3);
                        vb[((size_t)bb * 16 + h) * 131072 + (size_t)d * 2048 + (pos & ~63) + posl] = f2bf(v0);
                    } else if (n < 2) {             // d<32, partner at n+2 (d+32) same lane
                        float v1 = acc[m][n + 2][reg];
                        float2 cs = ropetab[pos * 32 + d];
                        size_t base = (((size_t)bb * 16 + h) * 2048 + pos) * 64;
                        float e0 = v0 * cs.x - v1 * cs.y;
                        float e1 = v1 * cs.x + v0 * cs.y;
                        if (part == 0) {            // q: fold softmax scale AND log2(e) for exp2 softmax
                            qb[base + d]      = f2bf(e0 * 0.18033688f);
                            qb[base + d + 32] = f2bf(e1 * 0.18033688f);
                        } else {                    // k row-swizzled
                            int sw = (pos & 7) << 3;
                            kb[base + (d ^ sw)]        = f2bf(e0);
                            kb[base + ((d + 32) ^ sw)] = f2bf(e1);
                        }
                    }
                }
            }
    }
}

// ---- flash attention (r12 structure): 8 waves x 16 q-rows; 3-deep LDS K/V; deferred PV ----
#define PST 68   // Ps row stride (ushorts)
__global__ __launch_bounds__(512, 4) void attn_kernel(
    const unsigned short* __restrict__ qbuf, const unsigned short* __restrict__ kbuf,
    const unsigned short* __restrict__ vtbuf, const unsigned long long* __restrict__ mbits,
    unsigned short* __restrict__ obuf)
{
    __shared__ __align__(16) unsigned short Ks[3][4096];   // [kvl][d^swz] 64x64
    __shared__ __align__(16) unsigned short Vs[3][4096];   // [d][kvl^swz] 64x64
    __shared__ __align__(16) unsigned short Ps[8][16][PST];

    int flat = blockIdx.x;
    int w = ((flat & 7) << 6) + (flat >> 3);
    int bh = w >> 4, qt = w & 15;
    int b = bh >> 4, h = bh & 15;
    int tid = threadIdx.x, wid = tid >> 6, lane = tid & 63, lr = lane & 15, lg = lane >> 4;
    int qrow0 = qt * 128 + wid * 16;
    const size_t bhbase = (size_t)bh * (2048 * 64);
    const unsigned short* kB = kbuf + bhbase;
    const unsigned short* vt = vtbuf + bhbase;
    const unsigned long long* mw = mbits + (b << 5);
    unsigned short* prow = &Ps[wid][lr][0];
    int sw3 = lr & 3;
    int swk = (lr & 7) << 3;

    bf16x8 qf[2];
    #pragma unroll
    for (int kk = 0; kk < 2; ++kk)
        qf[kk] = *(const bf16x8*)(qbuf + bhbase + (size_t)(qrow0 + lr) * 64 + kk * 32 + lg * 8);

    f32x4 oacc[4];
    #pragma unroll
    for (int n = 0; n < 4; ++n)
        #pragma unroll
        for (int i = 0; i < 4; ++i) oacc[n][i] = 0.0f;
    float mrow = -INFINITY, lrow = 0.f;   // lrow stays LANE-PARTIAL until epilogue
    const f32x4 z4 = {0.f, 0.f, 0.f, 0.f};

    bf16x8 pfp[2];        // pending P fragments (tile t-1); V(t-1) stays in LDS (3-buffer)

    auto stage = [&](int t, unsigned short* Kb, unsigned short* Vb) {
        gload_lds16(kB + (size_t)t * 4096 + tid * 8, Kb + wid * 512);
        gload_lds16(vt + (size_t)(tid >> 3) * 2048 + t * 64 + (tid & 7) * 8, Vb + wid * 512);
    };

    unsigned short *Kcur = Ks[0], *Knxt = Ks[1], *Kprv = Ks[2];
    unsigned short *Vcur = Vs[0], *Vnxt = Vs[1], *Vprv = Vs[2];

    stage(0, Kcur, Vcur);
    #pragma unroll 1
    for (int t = 0; t < 32; ++t) {
        __syncthreads();                  // staging of (t) complete; prior reads done
        if (t < 31) stage(t + 1, Knxt, Vnxt);
        unsigned long long bb = mw[t];    // wave-uniform mask word

        // K fragments (A-operand)
        bf16x8 kf[2][4];
        #pragma unroll
        for (int kk = 0; kk < 2; ++kk)
            #pragma unroll
            for (int n = 0; n < 4; ++n)
                kf[kk][n] = *(const bf16x8*)(Kcur + (n * 16 + lr) * 64 + ((kk * 32 + lg * 8) ^ swk));

        // MFMA cluster: QK^T(t), then deferred PV(t-1) with V read from LDS (short live range)
        __builtin_amdgcn_s_setprio(1);
        f32x4 sacc[4];
        #pragma unroll
        for (int n = 0; n < 4; ++n) {
            sacc[n] = __builtin_amdgcn_mfma_f32_16x16x32_bf16(kf[0][n], qf[0], z4, 0, 0, 0);
            sacc[n] = __builtin_amdgcn_mfma_f32_16x16x32_bf16(kf[1][n], qf[1], sacc[n], 0, 0, 0);
        }
        if (t) {
            #pragma unroll
            for (int kk2 = 0; kk2 < 2; ++kk2) {
                bf16x8 vf0 = *(const bf16x8*)(Vprv + (0 * 16 + lr) * 64 + ((kk2 * 32 + lg * 8) ^ swk));
                bf16x8 vf1 = *(const bf16x8*)(Vprv + (1 * 16 + lr) * 64 + ((kk2 * 32 + lg * 8) ^ swk));
                bf16x8 vf2 = *(const bf16x8*)(Vprv + (2 * 16 + lr) * 64 + ((kk2 * 32 + lg * 8) ^ swk));
                bf16x8 vf3 = *(const bf16x8*)(Vprv + (3 * 16 + lr) * 64 + ((kk2 * 32 + lg * 8) ^ swk));
                oacc[0] = __builtin_amdgcn_mfma_f32_16x16x32_bf16(pfp[kk2], vf0, oacc[0], 0, 0, 0);
                oacc[1] = __builtin_amdgcn_mfma_f32_16x16x32_bf16(pfp[kk2], vf1, oacc[1], 0, 0, 0);
                oacc[2] = __builtin_amdgcn_mfma_f32_16x16x32_bf16(pfp[kk2], vf2, oacc[2], 0, 0, 0);
                oacc[3] = __builtin_amdgcn_mfma_f32_16x16x32_bf16(pfp[kk2], vf3, oacc[3], 0, 0, 0);
            }
        }
        __builtin_amdgcn_s_setprio(0);

        // mask (fast path when all 64 live)
        if (bb != ~0ULL) {
            #pragma unroll
            for (int n = 0; n < 4; ++n)
                #pragma unroll
                for (int reg = 0; reg < 4; ++reg) {
                    int kv = n * 16 + lg * 4 + reg;
                    if (!((bb >> kv) & 1)) sacc[n][reg] = -1e30f;
                }
        }

        // lane-local max; cross-lane reduce+rescale only when defer bound threatened
        float a0 = fmaxf(fmaxf(sacc[0][0], sacc[0][1]), fmaxf(sacc[0][2], sacc[0][3]));
        float a1 = fmaxf(fmaxf(sacc[1][0], sacc[1][1]), fmaxf(sacc[1][2], sacc[1][3]));
        float a2 = fmaxf(fmaxf(sacc[2][0], sacc[2][1]), fmaxf(sacc[2][2], sacc[2][3]));
        float a3 = fmaxf(fmaxf(sacc[3][0], sacc[3][1]), fmaxf(sacc[3][2], sacc[3][3]));
        float tmax = fmaxf(fmaxf(a0, a1), fmaxf(a2, a3));
        if (__any(tmax > mrow + 8.f)) {    // slow path (rare after tile 0)
            float tr = fmaxf(tmax, __shfl_xor(tmax, 16));
            tr = fmaxf(tr, __shfl_xor(tr, 32));
            float mnew = fmaxf(mrow, tr);
            float sc = (mrow == -INFINITY) ? 0.f : __builtin_amdgcn_exp2f(mrow - mnew);
            lrow *= sc;
            mrow = mnew;
            #pragma unroll
            for (int reg = 0; reg < 4; ++reg) {
                float scq = __shfl(sc, lg * 4 + reg);
                #pragma unroll
                for (int n = 0; n < 4; ++n) oacc[n][reg] *= scq;
            }
        }

        // P = exp2(S - m), lane-partial sum, pack, swizzled Ps store
        float ps = 0.f;
        #pragma unroll
        for (int n = 0; n < 4; ++n) {
            float p0 = __builtin_amdgcn_exp2f(sacc[n][0] - mrow);
            float p1 = __builtin_amdgcn_exp2f(sacc[n][1] - mrow);
            float p2 = __builtin_amdgcn_exp2f(sacc[n][2] - mrow);
            float p3 = __builtin_amdgcn_exp2f(sacc[n][3] - mrow);
            ps += (p0 + p1) + (p2 + p3);
            ushort4 wv;
            wv.x = bfc(p0); wv.y = bfc(p1); wv.z = bfc(p2); wv.w = bfc(p3);
            int gb = 2 * n + (lg >> 1);
            int col = ((gb ^ sw3) << 3) + (lg & 1) * 4;
            *(ushort4*)(prow + col) = wv;
        }
        lrow += ps;                        // no shuffle: deferred to epilogue

        // reload pending P fragments for next iteration's PV
        #pragma unroll
        for (int kk2 = 0; kk2 < 2; ++kk2)
            pfp[kk2] = *(const bf16x8*)(prow + (((kk2 * 4 + lg) ^ sw3) << 3));

        // rotate 3-buffer
        unsigned short* tK = Kprv; Kprv = Kcur; Kcur = Knxt; Knxt = tK;
        unsigned short* tV = Vprv; Vprv = Vcur; Vcur = Vnxt; Vnxt = tV;
    }

    // flush final pending PV (V(31) is in Vprv after last rotation)
    #pragma unroll
    for (int kk2 = 0; kk2 < 2; ++kk2) {
        #pragma unroll
        for (int n = 0; n < 4; ++n) {
            bf16x8 vf = *(const bf16x8*)(Vprv + (n * 16 + lr) * 64 + ((kk2 * 32 + lg * 8) ^ swk));
            oacc[n] = __builtin_amdgcn_mfma_f32_16x16x32_bf16(pfp[kk2], vf, oacc[n], 0, 0, 0);
        }
    }

    // complete the deferred l reduction
    lrow += __shfl_xor(lrow, 16);
    lrow += __shfl_xor(lrow, 32);

    // epilogue: O rows q = lg*4+reg, cols d = n*16+lr; ob written PRE-SWIZZLED for gemm1
    #pragma unroll
    for (int reg = 0; reg < 4; ++reg) {
        float lq = __shfl(lrow, lg * 4 + reg);
        float linv = 1.0f / lq;
        int qrow = qrow0 + lg * 4 + reg;
        int qsw = qrow & 7;
        #pragma unroll
        for (int n = 0; n < 4; ++n) {
            int jj = n * 2 + (lr >> 3);
            int colsw = h * 64 + (((jj ^ qsw) & 7) << 3) + (lr & 7);
            obuf[((size_t)b * 2048 + qrow) * 1024 + colsw] = bfc(oacc[n][reg] * linv);
        }
    }
}

extern "C" void kernel_launch(void* const* d_in, const int* in_sizes, int n_in,
                              void* d_out, int out_size, void* d_ws, size_t ws_size,
                              hipStream_t stream) {
    const float* x      = (const float*)d_in[0];
    const int* key_mask = (const int*)d_in[1];
    const float* w_qkv  = (const float*)d_in[2];
    const float* w_proj = (const float*)d_in[3];
    float* out = (float*)d_out;

    char* ws = (char*)d_ws;
    unsigned short* qb  = (unsigned short*)(ws);
    unsigned short* kb  = (unsigned short*)(ws + 8388608);
    unsigned short* vtb = (unsigned short*)(ws + 16777216);
    unsigned short* xob = (unsigned short*)(ws + 25165824);  // xsw for gemm0, then ob for gemm1
    unsigned short* wqT = (unsigned short*)(ws + 33554432);
    unsigned short* wpT = (unsigned short*)(ws + 39845888);
    float2*         tab = (float2*)(ws + 41943040);
    unsigned long long* mb = (unsigned long long*)(ws + 42467328);

    dim3 blk(256);
    prep_all<<<dim3(6401), blk, 0, stream>>>(x, w_qkv, w_proj, key_mask, xob, wqT, wpT, tab, mb);
    gemm_kernel<0><<<dim3(768), blk, 0, stream>>>(xob, wqT, tab, qb, kb, vtb, nullptr, 3072);
    attn_kernel<<<dim3(512), dim3(512), 0, stream>>>(qb, kb, vtb, mb, xob);
    gemm_kernel<1><<<dim3(256), blk, 0, stream>>>(xob, wpT, nullptr, nullptr, nullptr, nullptr, out, 1024);
}

// Round 15
// 143.045 us; speedup vs baseline: 1.7869x; 1.0890x over previous
//
#include <hip/hip_runtime.h>
#include <hip/hip_bf16.h>
#include <math.h>

// B=2, L=2048, D=1024, H=16, Dh=64. M = B*L = 4096.
// prep_all: x -> bf16 SWIZZLED xsw; w_qkv/w_proj -> bf16 transposed SWIZZLED; rope table; mask bits
// gemm<0>:  xsw @ wqT + RoPE -> q*(0.125*log2e) (natural), k (row-XOR), v^T (row-tile-XOR)
// attn:     flash attention v10: 32x32 MFMA, 32 q-rows/wave, in-register softmax (T12),
//           3-deep LDS K/V, deferred-PV, 4 waves/block
// gemm<1>:  ob @ wpT -> f32 d_out

typedef __attribute__((ext_vector_type(8))) short bf16x8;
typedef __attribute__((ext_vector_type(4))) float f32x4;
typedef __attribute__((ext_vector_type(16))) float f32x16;

__device__ __forceinline__ unsigned short f2bf(float f) {
    union { float f; unsigned int u; } v; v.f = f;
    unsigned int u = v.u;
    return (unsigned short)((u + 0x7FFFu + ((u >> 16) & 1u)) >> 16);
}

__device__ __forceinline__ unsigned short bfc(float f) {
    union { __hip_bfloat16 h; unsigned short u; } c;
    c.h = __float2bfloat16(f);
    return c.u;
}

__device__ __forceinline__ unsigned cvtpk(float a, float b) {
    unsigned r;
    asm("v_cvt_pk_bf16_f32 %0, %1, %2" : "=v"(r) : "v"(a), "v"(b));
    return r;
}

__device__ __forceinline__ void gload_lds16(const unsigned short* g, unsigned short* l) {
    __builtin_amdgcn_global_load_lds(
        (const __attribute__((address_space(1))) void*)g,
        (__attribute__((address_space(3))) void*)l, 16, 0, 0);
}

// ---- fused prep: [0,2048) xbf | [2048,5120) wqT | [5120,6144) wpT | [6144,6400) rope | 6400 mbits ----
__global__ __launch_bounds__(256) void prep_all(
    const float* __restrict__ x, const float* __restrict__ w_qkv, const float* __restrict__ w_proj,
    const int* __restrict__ mask,
    unsigned short* __restrict__ xsw, unsigned short* __restrict__ wqT,
    unsigned short* __restrict__ wpT, float2* __restrict__ tab,
    unsigned long long* __restrict__ mb)
{
    __shared__ unsigned short t[32][34];
    int bid = blockIdx.x, tid = threadIdx.x;
    if (bid < 2048) {
        int i = bid * 256 + tid;
        int row = i >> 7, blk = i & 127;
        int swblk = (blk & ~7) | ((blk ^ row) & 7);
        const float* src = x + ((size_t)row << 10) + (blk << 3);
        float4 f0 = *(const float4*)(src);
        float4 f1 = *(const float4*)(src + 4);
        ushort4 h0, h1;
        h0.x = f2bf(f0.x); h0.y = f2bf(f0.y); h0.z = f2bf(f0.z); h0.w = f2bf(f0.w);
        h1.x = f2bf(f1.x); h1.y = f2bf(f1.y); h1.z = f2bf(f1.z); h1.w = f2bf(f1.w);
        ushort4* dst = (ushort4*)(xsw + ((size_t)row << 10) + (swblk << 3));
        dst[0] = h0; dst[1] = h1;
    } else if (bid < 6144) {
        const float* w; unsigned short* wT; int Ncols, u;
        if (bid < 5120) { w = w_qkv; wT = wqT; Ncols = 3072; u = bid - 2048; }
        else            { w = w_proj; wT = wpT; Ncols = 1024; u = bid - 5120; }
        int NBx = Ncols >> 5;
        int n0 = (u % NBx) * 32, k0 = (u / NBx) * 32;
        int r = tid >> 3, c4 = (tid & 7) * 4;
        float4 f = *(const float4*)(w + (size_t)(k0 + r) * Ncols + n0 + c4);
        t[c4 + 0][r] = f2bf(f.x);
        t[c4 + 1][r] = f2bf(f.y);
        t[c4 + 2][r] = f2bf(f.z);
        t[c4 + 3][r] = f2bf(f.w);
        __syncthreads();
        ushort4 o;
        o.x = t[r][c4]; o.y = t[r][c4 + 1]; o.z = t[r][c4 + 2]; o.w = t[r][c4 + 3];
        int n = n0 + r, k = k0 + c4;
        int ksw = (k & ~63) | ((((k >> 3) ^ n) & 7) << 3) | (k & 7);
        *(ushort4*)(wT + (size_t)n * 1024 + ksw) = o;
    } else if (bid < 6400) {
        int i = (bid - 6144) * 256 + tid;
        int pos = i >> 5, d = i & 31;
        float inv = expf(-0.28782313662f * (float)d);
        float ang = (float)pos * inv;
        float s, c;
        sincosf(ang, &s, &c);
        tab[i] = make_float2(c, s);
    } else if (tid < 64) {
        int b = tid >> 5, w = tid & 31;
        unsigned long long bits = 0;
        #pragma unroll 8
        for (int j = 0; j < 64; ++j)
            if (mask[b * 2048 + w * 64 + j]) bits |= (1ULL << j);
        mb[tid] = bits;
    }
}

// ---- main GEMM: 128x128 tile, BK=64, both operands bf16 swizzled via global_load_lds ----
template<int MODE>
__global__ __launch_bounds__(256) void gemm_kernel(
    const unsigned short* __restrict__ Asw, const unsigned short* __restrict__ BT,
    const float2* __restrict__ ropetab,
    unsigned short* __restrict__ qb, unsigned short* __restrict__ kb,
    unsigned short* __restrict__ vb, float* __restrict__ Cout, int N)
{
    const int K = 1024;
    __shared__ __align__(16) unsigned short As[128 * 64];
    __shared__ __align__(16) unsigned short Bs[128 * 64];
    int tid = threadIdx.x;
    int wid = tid >> 6, lane = tid & 63, lr = lane & 15, lg = lane >> 4;
    int wm = (wid >> 1) * 64, wn = (wid & 1) * 64;

    int NB = N >> 7;
    int per = NB * 4;
    int flat = blockIdx.x;
    int w = (flat & 7) * per + (flat >> 3);
    int row0 = (w / NB) * 128, col0 = (w % NB) * 128;

    int swk = (lr & 7) << 3;

    f32x4 acc[4][4];
    #pragma unroll
    for (int m = 0; m < 4; ++m)
        #pragma unroll
        for (int n = 0; n < 4; ++n)
            #pragma unroll
            for (int i = 0; i < 4; ++i) acc[m][n][i] = 0.0f;

    for (int k0 = 0; k0 < K; k0 += 64) {
        #pragma unroll
        for (int i = 0; i < 4; ++i) {
            int cbase = (i * 4 + wid) * 64;
            int c = cbase + lane;
            int r = c >> 3, cc = (c & 7) * 8;
            gload_lds16(BT + (size_t)(col0 + r) * K + k0 + cc, Bs + cbase * 8);
            gload_lds16(Asw + (size_t)(row0 + r) * K + k0 + cc, As + cbase * 8);
        }
        __syncthreads();
        #pragma unroll
        for (int kk = 0; kk < 2; ++kk) {
            bf16x8 af[4], bfr[4];
            #pragma unroll
            for (int m = 0; m < 4; ++m)
                af[m] = *(const bf16x8*)(&As[(wm + m * 16 + lr) * 64 + ((kk * 32 + lg * 8) ^ swk)]);
            #pragma unroll
            for (int n = 0; n < 4; ++n)
                bfr[n] = *(const bf16x8*)(&Bs[(wn + n * 16 + lr) * 64 + ((kk * 32 + lg * 8) ^ swk)]);
            #pragma unroll
            for (int m = 0; m < 4; ++m)
                #pragma unroll
                for (int n = 0; n < 4; ++n)
                    acc[m][n] = __builtin_amdgcn_mfma_f32_16x16x32_bf16(af[m], bfr[n], acc[m][n], 0, 0, 0);
        }
        __syncthreads();
    }

    if (MODE == 1) {
        #pragma unroll
        for (int m = 0; m < 4; ++m)
            #pragma unroll
            for (int reg = 0; reg < 4; ++reg) {
                int grow = row0 + wm + m * 16 + lg * 4 + reg;
                #pragma unroll
                for (int n = 0; n < 4; ++n)
                    Cout[(size_t)grow * N + col0 + wn + n * 16 + lr] = acc[m][n][reg];
            }
    } else {
        #pragma unroll
        for (int m = 0; m < 4; ++m)
            #pragma unroll
            for (int reg = 0; reg < 4; ++reg) {
                int grow = row0 + wm + m * 16 + lg * 4 + reg;
                int pos = grow & 2047;
                int bb = grow >> 11;
                #pragma unroll
                for (int n = 0; n < 4; ++n) {
                    int col = col0 + wn + n * 16 + lr;
                    int part = col >> 10;           // 0=q 1=k 2=v
                    int h = (col >> 6) & 15;
                    int d = col & 63;
                    float v0 = acc[m][n][reg];
                    if (part == 2) {
                        int posl = (pos & 63) ^ ((d & 7) << 3);
                        vb[((size_t)bb * 16 + h) * 131072 + (size_t)d * 2048 + (pos & ~63) + posl] = f2bf(v0);
                    } else if (n < 2) {             // d<32, partner at n+2 (d+32) same lane
                        float v1 = acc[m][n + 2][reg];
                        float2 cs = ropetab[pos * 32 + d];
                        size_t base = (((size_t)bb * 16 + h) * 2048 + pos) * 64;
                        float e0 = v0 * cs.x - v1 * cs.y;
                        float e1 = v1 * cs.x + v0 * cs.y;
                        if (part == 0) {            // q: fold softmax scale AND log2(e) for exp2 softmax
                            qb[base + d]      = f2bf(e0 * 0.18033688f);
                            qb[base + d + 32] = f2bf(e1 * 0.18033688f);
                        } else {                    // k row-swizzled
                            int sw = (pos & 7) << 3;
                            kb[base + (d ^ sw)]        = f2bf(e0);
                            kb[base + ((d + 32) ^ sw)] = f2bf(e1);
                        }
                    }
                }
            }
    }
}

// ---- flash attention v10: 32x32 MFMA, 32 q/wave, T12 in-register softmax ----
__global__ __launch_bounds__(256, 2) void attn_kernel(
    const unsigned short* __restrict__ qbuf, const unsigned short* __restrict__ kbuf,
    const unsigned short* __restrict__ vtbuf, const unsigned long long* __restrict__ mbits,
    unsigned short* __restrict__ obuf)
{
    __shared__ __align__(16) unsigned short Ks[3][4096];   // [kvl][d^swz] 64x64
    __shared__ __align__(16) unsigned short Vs[3][4096];   // [d][kvl^swz] 64x64

    // XCD-chunked remap: 512 blocks, 8 XCDs, 64 consecutive w per XCD (4 bh -> 2MB K/V in L2)
    int flat = blockIdx.x;
    int w = ((flat & 7) << 6) + (flat >> 3);
    int bh = w >> 4, qt = w & 15;
    int b = bh >> 4, h = bh & 15;
    int tid = threadIdx.x, wid = tid >> 6, lane = tid & 63;
    int l31 = lane & 31, hi = lane >> 5, hi8 = hi << 3;
    int qrow0 = qt * 128 + wid * 32;
    const size_t bhbase = (size_t)bh * (2048 * 64);
    const unsigned short* kB = kbuf + bhbase;
    const unsigned short* vt = vtbuf + bhbase;
    const unsigned long long* mw = mbits + (b << 5);
    int swl = (l31 & 7) << 3;                      // LDS read de-swizzle

    // Q fragments (B-operand for 32x32x16): q = l31, k-slice s: k = 16s + 8hi + j
    bf16x8 qf[4];
    #pragma unroll
    for (int s = 0; s < 4; ++s)
        qf[s] = *(const bf16x8*)(qbuf + bhbase + (size_t)(qrow0 + l31) * 64 + s * 16 + hi8);

    f32x16 oacc[2];
    #pragma unroll
    for (int db = 0; db < 2; ++db)
        #pragma unroll
        for (int i = 0; i < 16; ++i) oacc[db][i] = 0.0f;
    float mrow = -INFINITY, lrow = 0.f;            // per q = l31 (row-uniform across hi)
    bf16x8 pfp[4];                                 // pending P fragments (tile t-1)

    auto stage = [&](int t, unsigned short* Kb, unsigned short* Vb) {
        #pragma unroll
        for (int i = 0; i < 2; ++i) {
            int idx = i * 256 + tid;
            gload_lds16(kB + (size_t)t * 4096 + idx * 8, Kb + i * 2048 + wid * 512);
            gload_lds16(vt + (size_t)(idx >> 3) * 2048 + t * 64 + (idx & 7) * 8, Vb + i * 2048 + wid * 512);
        }
    };

    unsigned short *Kcur = Ks[0], *Knxt = Ks[1], *Kprv = Ks[2];
    unsigned short *Vcur = Vs[0], *Vnxt = Vs[1], *Vprv = Vs[2];

    stage(0, Kcur, Vcur);
    #pragma unroll 1
    for (int t = 0; t < 32; ++t) {
        __syncthreads();                  // staging of (t) complete; prior reads done
        if (t < 31) stage(t + 1, Knxt, Vnxt);
        unsigned long long bb = mw[t];    // wave-uniform mask word

        // MFMA cluster: QK^T(t) (8x 32x32x16), then deferred PV(t-1) (8x)
        __builtin_amdgcn_s_setprio(1);
        f32x16 sacc[2];
        #pragma unroll
        for (int ka = 0; ka < 2; ++ka)
            #pragma unroll
            for (int i = 0; i < 16; ++i) sacc[ka][i] = 0.0f;
        #pragma unroll
        for (int s = 0; s < 4; ++s)
            #pragma unroll
            for (int ka = 0; ka < 2; ++ka) {
                bf16x8 kfx = *(const bf16x8*)(Kcur + (ka * 32 + l31) * 64 + ((s * 16 + hi8) ^ swl));
                sacc[ka] = __builtin_amdgcn_mfma_f32_32x32x16_bf16(kfx, qf[s], sacc[ka], 0, 0, 0);
            }
        if (t) {
            #pragma unroll
            for (int s = 0; s < 4; ++s)
                #pragma unroll
                for (int db = 0; db < 2; ++db) {
                    bf16x8 vfx = *(const bf16x8*)(Vprv + (db * 32 + l31) * 64 + ((s * 16 + hi8) ^ swl));
                    oacc[db] = __builtin_amdgcn_mfma_f32_32x32x16_bf16(pfp[s], vfx, oacc[db], 0, 0, 0);
                }
        }
        __builtin_amdgcn_s_setprio(0);

        // mask (fast path when all 64 live); kv = 32kb + (reg&3) + 8*(reg>>2) + 4*hi
        if (bb != ~0ULL) {
            int hi4 = hi << 2;
            #pragma unroll
            for (int kb = 0; kb < 2; ++kb)
                #pragma unroll
                for (int reg = 0; reg < 16; ++reg) {
                    int kv = kb * 32 + (reg & 3) + ((reg >> 2) << 3) + hi4;
                    if (!((bb >> kv) & 1)) sacc[kb][reg] = -1e30f;
                }
        }

        // row max: lane-local (32 vals) + 1 shfl_xor(32) -> row-uniform
        float tmax = sacc[0][0];
        #pragma unroll
        for (int kb = 0; kb < 2; ++kb)
            #pragma unroll
            for (int reg = 0; reg < 16; ++reg)
                if (kb | reg) tmax = fmaxf(tmax, sacc[kb][reg]);
        tmax = fmaxf(tmax, __shfl_xor(tmax, 32));

        // defer-max rescale (T13, THR=8); slow path rare after tile 0
        if (__any(tmax > mrow + 8.f)) {
            float mnew = fmaxf(mrow, tmax);
            float sc = (mrow == -INFINITY) ? 0.f : __builtin_amdgcn_exp2f(mrow - mnew);
            lrow *= sc;
            mrow = mnew;
            #pragma unroll
            for (int reg = 0; reg < 16; ++reg) {
                int qof = (reg & 3) + ((reg >> 2) << 3) + (hi << 2);
                float scq = __shfl(sc, qof);
                oacc[0][reg] *= scq;
                oacc[1][reg] *= scq;
            }
        }

        // P = exp2(S - m) in place, lane-partial row sum
        float ps = 0.f;
        #pragma unroll
        for (int kb = 0; kb < 2; ++kb)
            #pragma unroll
            for (int reg = 0; reg < 16; ++reg) {
                float pv = __builtin_amdgcn_exp2f(sacc[kb][reg] - mrow);
                sacc[kb][reg] = pv;
                ps += pv;
            }
        lrow += ps;

        // T12 pack: per kv-slice s: 4 cvt_pk + 2 permlane32_swap -> A-frag (q=l31, kv=16s+8hi+j)
        #pragma unroll
        for (int s = 0; s < 4; ++s) {
            int kb = s >> 1, ra = (s & 1) * 8;
            unsigned wA0 = cvtpk(sacc[kb][ra + 0], sacc[kb][ra + 1]);
            unsigned wA1 = cvtpk(sacc[kb][ra + 2], sacc[kb][ra + 3]);
            unsigned wB0 = cvtpk(sacc[kb][ra + 4], sacc[kb][ra + 5]);
            unsigned wB1 = cvtpk(sacc[kb][ra + 6], sacc[kb][ra + 7]);
            asm("v_permlane32_swap_b32 %0, %1" : "+v"(wA0), "+v"(wB0));
            asm("v_permlane32_swap_b32 %0, %1" : "+v"(wA1), "+v"(wB1));
            union { unsigned u[4]; bf16x8 v; } pk;
            pk.u[0] = wA0; pk.u[1] = wA1; pk.u[2] = wB0; pk.u[3] = wB1;
            pfp[s] = pk.v;
        }

        // rotate 3-buffer
        unsigned short* tK = Kprv; Kprv = Kcur; Kcur = Knxt; Knxt = tK;
        unsigned short* tV = Vprv; Vprv = Vcur; Vcur = Vnxt; Vnxt = tV;
    }

    // flush final pending PV (V(31) is in Vprv after last rotation)
    #pragma unroll
    for (int s = 0; s < 4; ++s)
        #pragma unroll
        for (int db = 0; db < 2; ++db) {
            bf16x8 vfx = *(const bf16x8*)(Vprv + (db * 32 + l31) * 64 + ((s * 16 + hi8) ^ swl));
            oacc[db] = __builtin_amdgcn_mfma_f32_32x32x16_bf16(pfp[s], vfx, oacc[db], 0, 0, 0);
        }

    // complete deferred l reduction (row-uniform)
    lrow += __shfl_xor(lrow, 32);

    // epilogue: O rows q = (reg&3)+8*(reg>>2)+4*hi, cols d = db*32 + l31; pre-swizzled for gemm1
    #pragma unroll
    for (int reg = 0; reg < 16; ++reg) {
        int qof = (reg & 3) + ((reg >> 2) << 3) + (hi << 2);
        float lq = __shfl(lrow, qof);
        float linv = 1.0f / lq;
        int qrow = qrow0 + qof;
        int qsw = qrow & 7;
        #pragma unroll
        for (int db = 0; db < 2; ++db) {
            int dcol = db * 32 + l31;
            int jj = dcol >> 3;
            int colsw = h * 64 + (((jj ^ qsw) & 7) << 3) + (dcol & 7);
            obuf[((size_t)b * 2048 + qrow) * 1024 + colsw] = bfc(oacc[db][reg] * linv);
        }
    }
}

extern "C" void kernel_launch(void* const* d_in, const int* in_sizes, int n_in,
                              void* d_out, int out_size, void* d_ws, size_t ws_size,
                              hipStream_t stream) {
    const float* x      = (const float*)d_in[0];
    const int* key_mask = (const int*)d_in[1];
    const float* w_qkv  = (const float*)d_in[2];
    const float* w_proj = (const float*)d_in[3];
    float* out = (float*)d_out;

    char* ws = (char*)d_ws;
    unsigned short* qb  = (unsigned short*)(ws);
    unsigned short* kb  = (unsigned short*)(ws + 8388608);
    unsigned short* vtb = (unsigned short*)(ws + 16777216);
    unsigned short* xob = (unsigned short*)(ws + 25165824);  // xsw for gemm0, then ob for gemm1
    unsigned short* wqT = (unsigned short*)(ws + 33554432);
    unsigned short* wpT = (unsigned short*)(ws + 39845888);
    float2*         tab = (float2*)(ws + 41943040);
    unsigned long long* mb = (unsigned long long*)(ws + 42467328);

    dim3 blk(256);
    prep_all<<<dim3(6401), blk, 0, stream>>>(x, w_qkv, w_proj, key_mask, xob, wqT, wpT, tab, mb);
    gemm_kernel<0><<<dim3(768), blk, 0, stream>>>(xob, wqT, tab, qb, kb, vtb, nullptr, 3072);
    attn_kernel<<<dim3(512), blk, 0, stream>>>(qb, kb, vtb, mb, xob);
    gemm_kernel<1><<<dim3(256), blk, 0, stream>>>(xob, wpT, nullptr, nullptr, nullptr, nullptr, out, 1024);
}

// Round 16
// 122.097 us; speedup vs baseline: 2.0935x; 1.1716x over previous
//
#include <hip/hip_runtime.h>
#include <hip/hip_bf16.h>
#include <math.h>

// B=2, L=2048, D=1024, H=16, Dh=64. M = B*L = 4096.
// prep_all: x -> bf16 SWIZZLED xsw; w_qkv/w_proj -> bf16 transposed SWIZZLED; rope table; mask bits
// gemm<0>:  xsw @ wqT + RoPE -> q*(0.125*log2e) (natural), k (row-XOR), v^T (row-tile-XOR)
//           tile 128x64, 4 waves x (32 rows x 64 cols), grid 1536 (6 blocks/CU)
// attn:     flash attention v10: 32x32 MFMA, 32 q-rows/wave, in-register softmax (T12)
// gemm<1>:  ob @ wpT -> f32 d_out; tile 128x64, grid 512

typedef __attribute__((ext_vector_type(8))) short bf16x8;
typedef __attribute__((ext_vector_type(4))) float f32x4;
typedef __attribute__((ext_vector_type(16))) float f32x16;

__device__ __forceinline__ unsigned short f2bf(float f) {
    union { float f; unsigned int u; } v; v.f = f;
    unsigned int u = v.u;
    return (unsigned short)((u + 0x7FFFu + ((u >> 16) & 1u)) >> 16);
}

__device__ __forceinline__ unsigned short bfc(float f) {
    union { __hip_bfloat16 h; unsigned short u; } c;
    c.h = __float2bfloat16(f);
    return c.u;
}

__device__ __forceinline__ unsigned cvtpk(float a, float b) {
    unsigned r;
    asm("v_cvt_pk_bf16_f32 %0, %1, %2" : "=v"(r) : "v"(a), "v"(b));
    return r;
}

__device__ __forceinline__ void gload_lds16(const unsigned short* g, unsigned short* l) {
    __builtin_amdgcn_global_load_lds(
        (const __attribute__((address_space(1))) void*)g,
        (__attribute__((address_space(3))) void*)l, 16, 0, 0);
}

// ---- fused prep: [0,2048) xbf | [2048,5120) wqT | [5120,6144) wpT | [6144,6400) rope | 6400 mbits ----
__global__ __launch_bounds__(256) void prep_all(
    const float* __restrict__ x, const float* __restrict__ w_qkv, const float* __restrict__ w_proj,
    const int* __restrict__ mask,
    unsigned short* __restrict__ xsw, unsigned short* __restrict__ wqT,
    unsigned short* __restrict__ wpT, float2* __restrict__ tab,
    unsigned long long* __restrict__ mb)
{
    __shared__ unsigned short t[32][34];
    int bid = blockIdx.x, tid = threadIdx.x;
    if (bid < 2048) {
        int i = bid * 256 + tid;
        int row = i >> 7, blk = i & 127;
        int swblk = (blk & ~7) | ((blk ^ row) & 7);
        const float* src = x + ((size_t)row << 10) + (blk << 3);
        float4 f0 = *(const float4*)(src);
        float4 f1 = *(const float4*)(src + 4);
        ushort4 h0, h1;
        h0.x = f2bf(f0.x); h0.y = f2bf(f0.y); h0.z = f2bf(f0.z); h0.w = f2bf(f0.w);
        h1.x = f2bf(f1.x); h1.y = f2bf(f1.y); h1.z = f2bf(f1.z); h1.w = f2bf(f1.w);
        ushort4* dst = (ushort4*)(xsw + ((size_t)row << 10) + (swblk << 3));
        dst[0] = h0; dst[1] = h1;
    } else if (bid < 6144) {
        const float* w; unsigned short* wT; int Ncols, u;
        if (bid < 5120) { w = w_qkv; wT = wqT; Ncols = 3072; u = bid - 2048; }
        else            { w = w_proj; wT = wpT; Ncols = 1024; u = bid - 5120; }
        int NBx = Ncols >> 5;
        int n0 = (u % NBx) * 32, k0 = (u / NBx) * 32;
        int r = tid >> 3, c4 = (tid & 7) * 4;
        float4 f = *(const float4*)(w + (size_t)(k0 + r) * Ncols + n0 + c4);
        t[c4 + 0][r] = f2bf(f.x);
        t[c4 + 1][r] = f2bf(f.y);
        t[c4 + 2][r] = f2bf(f.z);
        t[c4 + 3][r] = f2bf(f.w);
        __syncthreads();
        ushort4 o;
        o.x = t[r][c4]; o.y = t[r][c4 + 1]; o.z = t[r][c4 + 2]; o.w = t[r][c4 + 3];
        int n = n0 + r, k = k0 + c4;
        int ksw = (k & ~63) | ((((k >> 3) ^ n) & 7) << 3) | (k & 7);
        *(ushort4*)(wT + (size_t)n * 1024 + ksw) = o;
    } else if (bid < 6400) {
        int i = (bid - 6144) * 256 + tid;
        int pos = i >> 5, d = i & 31;
        float inv = expf(-0.28782313662f * (float)d);
        float ang = (float)pos * inv;
        float s, c;
        sincosf(ang, &s, &c);
        tab[i] = make_float2(c, s);
    } else if (tid < 64) {
        int b = tid >> 5, w = tid & 31;
        unsigned long long bits = 0;
        #pragma unroll 8
        for (int j = 0; j < 64; ++j)
            if (mask[b * 2048 + w * 64 + j]) bits |= (1ULL << j);
        mb[tid] = bits;
    }
}

// ---- main GEMM: 128x64 tile, BK=64, 4 waves x (32 rows x 64 cols), NB = col panels ----
template<int MODE>
__global__ __launch_bounds__(256) void gemm_kernel(
    const unsigned short* __restrict__ Asw, const unsigned short* __restrict__ BT,
    const float2* __restrict__ ropetab,
    unsigned short* __restrict__ qb, unsigned short* __restrict__ kb,
    unsigned short* __restrict__ vb, float* __restrict__ Cout, int NB)
{
    const int K = 1024;
    __shared__ __align__(16) unsigned short As[128 * 64];   // 16 KB
    __shared__ __align__(16) unsigned short Bs[64 * 64];    //  8 KB
    int tid = threadIdx.x;
    int wid = tid >> 6, lane = tid & 63, lr = lane & 15, lg = lane >> 4;
    int wm = wid * 32;

    // XCD-chunked 1D grid: 32 row panels; each XCD owns 4 consecutive row panels x all NB cols
    int per = NB * 4;
    int flat = blockIdx.x;
    int w = (flat & 7) * per + (flat >> 3);
    int row0 = (w / NB) * 128, col0 = (w % NB) * 64;

    int swk = (lr & 7) << 3;         // LDS read de-swizzle (elements)

    f32x4 acc[2][4];
    #pragma unroll
    for (int m = 0; m < 2; ++m)
        #pragma unroll
        for (int n = 0; n < 4; ++n)
            #pragma unroll
            for (int i = 0; i < 4; ++i) acc[m][n][i] = 0.0f;

    for (int k0 = 0; k0 < K; k0 += 64) {
        // B tile: 64 rows (out-cols) x 64 k = 512 chunks (2/thread)
        #pragma unroll
        for (int i = 0; i < 2; ++i) {
            int cbase = (i * 4 + wid) * 64;
            int c = cbase + lane;
            int r = c >> 3, cc = (c & 7) * 8;
            gload_lds16(BT + (size_t)(col0 + r) * K + k0 + cc, Bs + cbase * 8);
        }
        // A tile: 128 rows x 64 k = 1024 chunks (4/thread)
        #pragma unroll
        for (int i = 0; i < 4; ++i) {
            int cbase = (i * 4 + wid) * 64;
            int c = cbase + lane;
            int r = c >> 3, cc = (c & 7) * 8;
            gload_lds16(Asw + (size_t)(row0 + r) * K + k0 + cc, As + cbase * 8);
        }
        __syncthreads();
        #pragma unroll
        for (int kk = 0; kk < 2; ++kk) {
            bf16x8 af[2], bfr[4];
            #pragma unroll
            for (int m = 0; m < 2; ++m)
                af[m] = *(const bf16x8*)(&As[(wm + m * 16 + lr) * 64 + ((kk * 32 + lg * 8) ^ swk)]);
            #pragma unroll
            for (int n = 0; n < 4; ++n)
                bfr[n] = *(const bf16x8*)(&Bs[(n * 16 + lr) * 64 + ((kk * 32 + lg * 8) ^ swk)]);
            #pragma unroll
            for (int m = 0; m < 2; ++m)
                #pragma unroll
                for (int n = 0; n < 4; ++n)
                    acc[m][n] = __builtin_amdgcn_mfma_f32_16x16x32_bf16(af[m], bfr[n], acc[m][n], 0, 0, 0);
        }
        __syncthreads();
    }

    if (MODE == 1) {
        int N = NB * 64;
        #pragma unroll
        for (int m = 0; m < 2; ++m)
            #pragma unroll
            for (int reg = 0; reg < 4; ++reg) {
                int grow = row0 + wm + m * 16 + lg * 4 + reg;
                #pragma unroll
                for (int n = 0; n < 4; ++n)
                    Cout[(size_t)grow * N + col0 + n * 16 + lr] = acc[m][n][reg];
            }
    } else {
        #pragma unroll
        for (int m = 0; m < 2; ++m)
            #pragma unroll
            for (int reg = 0; reg < 4; ++reg) {
                int grow = row0 + wm + m * 16 + lg * 4 + reg;
                int pos = grow & 2047;
                int bb = grow >> 11;
                #pragma unroll
                for (int n = 0; n < 4; ++n) {
                    int col = col0 + n * 16 + lr;
                    int part = col >> 10;           // 0=q 1=k 2=v
                    int h = (col >> 6) & 15;
                    int d = col & 63;               // = n*16 + lr (64-aligned head tiles)
                    float v0 = acc[m][n][reg];
                    if (part == 2) {
                        int posl = (pos & 63) ^ ((d & 7) << 3);
                        vb[((size_t)bb * 16 + h) * 131072 + (size_t)d * 2048 + (pos & ~63) + posl] = f2bf(v0);
                    } else if (n < 2) {             // d<32, partner at n+2 (d+32) same lane
                        float v1 = acc[m][n + 2][reg];
                        float2 cs = ropetab[pos * 32 + d];
                        size_t base = (((size_t)bb * 16 + h) * 2048 + pos) * 64;
                        float e0 = v0 * cs.x - v1 * cs.y;
                        float e1 = v1 * cs.x + v0 * cs.y;
                        if (part == 0) {            // q: fold softmax scale AND log2(e) for exp2 softmax
                            qb[base + d]      = f2bf(e0 * 0.18033688f);
                            qb[base + d + 32] = f2bf(e1 * 0.18033688f);
                        } else {                    // k row-swizzled
                            int sw = (pos & 7) << 3;
                            kb[base + (d ^ sw)]        = f2bf(e0);
                            kb[base + ((d + 32) ^ sw)] = f2bf(e1);
                        }
                    }
                }
            }
    }
}

// ---- flash attention v10: 32x32 MFMA, 32 q/wave, T12 in-register softmax ----
__global__ __launch_bounds__(256, 2) void attn_kernel(
    const unsigned short* __restrict__ qbuf, const unsigned short* __restrict__ kbuf,
    const unsigned short* __restrict__ vtbuf, const unsigned long long* __restrict__ mbits,
    unsigned short* __restrict__ obuf)
{
    __shared__ __align__(16) unsigned short Ks[3][4096];   // [kvl][d^swz] 64x64
    __shared__ __align__(16) unsigned short Vs[3][4096];   // [d][kvl^swz] 64x64

    int flat = blockIdx.x;
    int w = ((flat & 7) << 6) + (flat >> 3);
    int bh = w >> 4, qt = w & 15;
    int b = bh >> 4, h = bh & 15;
    int tid = threadIdx.x, wid = tid >> 6, lane = tid & 63;
    int l31 = lane & 31, hi = lane >> 5, hi8 = hi << 3;
    int qrow0 = qt * 128 + wid * 32;
    const size_t bhbase = (size_t)bh * (2048 * 64);
    const unsigned short* kB = kbuf + bhbase;
    const unsigned short* vt = vtbuf + bhbase;
    const unsigned long long* mw = mbits + (b << 5);
    int swl = (l31 & 7) << 3;                      // LDS read de-swizzle

    bf16x8 qf[4];
    #pragma unroll
    for (int s = 0; s < 4; ++s)
        qf[s] = *(const bf16x8*)(qbuf + bhbase + (size_t)(qrow0 + l31) * 64 + s * 16 + hi8);

    f32x16 oacc[2];
    #pragma unroll
    for (int db = 0; db < 2; ++db)
        #pragma unroll
        for (int i = 0; i < 16; ++i) oacc[db][i] = 0.0f;
    float mrow = -INFINITY, lrow = 0.f;
    bf16x8 pfp[4];

    auto stage = [&](int t, unsigned short* Kb, unsigned short* Vb) {
        #pragma unroll
        for (int i = 0; i < 2; ++i) {
            int idx = i * 256 + tid;
            gload_lds16(kB + (size_t)t * 4096 + idx * 8, Kb + i * 2048 + wid * 512);
            gload_lds16(vt + (size_t)(idx >> 3) * 2048 + t * 64 + (idx & 7) * 8, Vb + i * 2048 + wid * 512);
        }
    };

    unsigned short *Kcur = Ks[0], *Knxt = Ks[1], *Kprv = Ks[2];
    unsigned short *Vcur = Vs[0], *Vnxt = Vs[1], *Vprv = Vs[2];

    stage(0, Kcur, Vcur);
    #pragma unroll 1
    for (int t = 0; t < 32; ++t) {
        __syncthreads();
        if (t < 31) stage(t + 1, Knxt, Vnxt);
        unsigned long long bb = mw[t];

        __builtin_amdgcn_s_setprio(1);
        f32x16 sacc[2];
        #pragma unroll
        for (int ka = 0; ka < 2; ++ka)
            #pragma unroll
            for (int i = 0; i < 16; ++i) sacc[ka][i] = 0.0f;
        #pragma unroll
        for (int s = 0; s < 4; ++s)
            #pragma unroll
            for (int ka = 0; ka < 2; ++ka) {
                bf16x8 kfx = *(const bf16x8*)(Kcur + (ka * 32 + l31) * 64 + ((s * 16 + hi8) ^ swl));
                sacc[ka] = __builtin_amdgcn_mfma_f32_32x32x16_bf16(kfx, qf[s], sacc[ka], 0, 0, 0);
            }
        if (t) {
            #pragma unroll
            for (int s = 0; s < 4; ++s)
                #pragma unroll
                for (int db = 0; db < 2; ++db) {
                    bf16x8 vfx = *(const bf16x8*)(Vprv + (db * 32 + l31) * 64 + ((s * 16 + hi8) ^ swl));
                    oacc[db] = __builtin_amdgcn_mfma_f32_32x32x16_bf16(pfp[s], vfx, oacc[db], 0, 0, 0);
                }
        }
        __builtin_amdgcn_s_setprio(0);

        if (bb != ~0ULL) {
            int hi4 = hi << 2;
            #pragma unroll
            for (int kb = 0; kb < 2; ++kb)
                #pragma unroll
                for (int reg = 0; reg < 16; ++reg) {
                    int kv = kb * 32 + (reg & 3) + ((reg >> 2) << 3) + hi4;
                    if (!((bb >> kv) & 1)) sacc[kb][reg] = -1e30f;
                }
        }

        float tmax = sacc[0][0];
        #pragma unroll
        for (int kb = 0; kb < 2; ++kb)
            #pragma unroll
            for (int reg = 0; reg < 16; ++reg)
                if (kb | reg) tmax = fmaxf(tmax, sacc[kb][reg]);
        tmax = fmaxf(tmax, __shfl_xor(tmax, 32));

        if (__any(tmax > mrow + 8.f)) {
            float mnew = fmaxf(mrow, tmax);
            float sc = (mrow == -INFINITY) ? 0.f : __builtin_amdgcn_exp2f(mrow - mnew);
            lrow *= sc;
            mrow = mnew;
            #pragma unroll
            for (int reg = 0; reg < 16; ++reg) {
                int qof = (reg & 3) + ((reg >> 2) << 3) + (hi << 2);
                float scq = __shfl(sc, qof);
                oacc[0][reg] *= scq;
                oacc[1][reg] *= scq;
            }
        }

        float ps = 0.f;
        #pragma unroll
        for (int kb = 0; kb < 2; ++kb)
            #pragma unroll
            for (int reg = 0; reg < 16; ++reg) {
                float pv = __builtin_amdgcn_exp2f(sacc[kb][reg] - mrow);
                sacc[kb][reg] = pv;
                ps += pv;
            }
        lrow += ps;

        #pragma unroll
        for (int s = 0; s < 4; ++s) {
            int kb = s >> 1, ra = (s & 1) * 8;
            unsigned wA0 = cvtpk(sacc[kb][ra + 0], sacc[kb][ra + 1]);
            unsigned wA1 = cvtpk(sacc[kb][ra + 2], sacc[kb][ra + 3]);
            unsigned wB0 = cvtpk(sacc[kb][ra + 4], sacc[kb][ra + 5]);
            unsigned wB1 = cvtpk(sacc[kb][ra + 6], sacc[kb][ra + 7]);
            asm("v_permlane32_swap_b32 %0, %1" : "+v"(wA0), "+v"(wB0));
            asm("v_permlane32_swap_b32 %0, %1" : "+v"(wA1), "+v"(wB1));
            union { unsigned u[4]; bf16x8 v; } pk;
            pk.u[0] = wA0; pk.u[1] = wA1; pk.u[2] = wB0; pk.u[3] = wB1;
            pfp[s] = pk.v;
        }

        unsigned short* tK = Kprv; Kprv = Kcur; Kcur = Knxt; Knxt = tK;
        unsigned short* tV = Vprv; Vprv = Vcur; Vcur = Vnxt; Vnxt = tV;
    }

    #pragma unroll
    for (int s = 0; s < 4; ++s)
        #pragma unroll
        for (int db = 0; db < 2; ++db) {
            bf16x8 vfx = *(const bf16x8*)(Vprv + (db * 32 + l31) * 64 + ((s * 16 + hi8) ^ swl));
            oacc[db] = __builtin_amdgcn_mfma_f32_32x32x16_bf16(pfp[s], vfx, oacc[db], 0, 0, 0);
        }

    lrow += __shfl_xor(lrow, 32);

    #pragma unroll
    for (int reg = 0; reg < 16; ++reg) {
        int qof = (reg & 3) + ((reg >> 2) << 3) + (hi << 2);
        float lq = __shfl(lrow, qof);
        float linv = 1.0f / lq;
        int qrow = qrow0 + qof;
        int qsw = qrow & 7;
        #pragma unroll
        for (int db = 0; db < 2; ++db) {
            int dcol = db * 32 + l31;
            int jj = dcol >> 3;
            int colsw = h * 64 + (((jj ^ qsw) & 7) << 3) + (dcol & 7);
            obuf[((size_t)b * 2048 + qrow) * 1024 + colsw] = bfc(oacc[db][reg] * linv);
        }
    }
}

extern "C" void kernel_launch(void* const* d_in, const int* in_sizes, int n_in,
                              void* d_out, int out_size, void* d_ws, size_t ws_size,
                              hipStream_t stream) {
    const float* x      = (const float*)d_in[0];
    const int* key_mask = (const int*)d_in[1];
    const float* w_qkv  = (const float*)d_in[2];
    const float* w_proj = (const float*)d_in[3];
    float* out = (float*)d_out;

    char* ws = (char*)d_ws;
    unsigned short* qb  = (unsigned short*)(ws);
    unsigned short* kb  = (unsigned short*)(ws + 8388608);
    unsigned short* vtb = (unsigned short*)(ws + 16777216);
    unsigned short* xob = (unsigned short*)(ws + 25165824);  // xsw for gemm0, then ob for gemm1
    unsigned short* wqT = (unsigned short*)(ws + 33554432);
    unsigned short* wpT = (unsigned short*)(ws + 39845888);
    float2*         tab = (float2*)(ws + 41943040);
    unsigned long long* mb = (unsigned long long*)(ws + 42467328);

    dim3 blk(256);
    prep_all<<<dim3(6401), blk, 0, stream>>>(x, w_qkv, w_proj, key_mask, xob, wqT, wpT, tab, mb);
    // gemm0: 32 row panels x 48 col panels = 1536 blocks (6/CU)
    gemm_kernel<0><<<dim3(1536), blk, 0, stream>>>(xob, wqT, tab, qb, kb, vtb, nullptr, 48);
    attn_kernel<<<dim3(512), blk, 0, stream>>>(qb, kb, vtb, mb, xob);
    // gemm1: 32 row panels x 16 col panels = 512 blocks (2/CU)
    gemm_kernel<1><<<dim3(512), blk, 0, stream>>>(xob, wpT, nullptr, nullptr, nullptr, nullptr, out, 16);
}